// Round 5
// baseline (281.840 us; speedup 1.0000x reference)
//
#include <hip/hip_runtime.h>

// ---------------------------------------------------------------------------
// Downsampling — fp16 MFMA, BK=64, split-K x2 GEMMs (4 blocks/CU).
//   prep:    M1T (even rows + odd>=961), M2T, A1 transpose       [9216 blocks]
//   gemm1:   fe{0,1}[8192][512]f16 = A1 @ (even rows of M1T)^T, K split 2x512
//   ola_pack: fr[4096][1024]f16 = frame(decimate(OLA(fe0+fe1)))
//            odd-tail samples via direct 1024-dots (t=126 only)
//   gemm2:   out += fr @ M2T^T (split-K, f32 atomicAdd onto zeroed d_out)
// ---------------------------------------------------------------------------

#define WIN       1022
#define HOP       256
#define T_IN      127
#define NB        64
#define NPAD      1024
#define NE        512       // even-compacted stage-1 columns; also K per z-slice
#define T_OUT     62
#define HALF_KEPT 16608     // 33216/2
#define L_USE     16638     // kept samples beyond 16637 feed no output frame
#define ROWS1     8128
#define ROWS1P    8192
#define ROWS2     3968
#define ROWS2P    4096
#define TWO_PI_F  6.28318530717958647692f

typedef _Float16 half8 __attribute__((ext_vector_type(8)));
typedef float    f32x4 __attribute__((ext_vector_type(4)));

// ------------------------------- fused prep --------------------------------
__global__ __launch_bounds__(256) void prep(const float* __restrict__ in,
                                            _Float16* __restrict__ M1T,
                                            _Float16* __restrict__ M2T,
                                            _Float16* __restrict__ A1) {
    __shared__ float lds[32 * 254];
    int bx = blockIdx.x, tid = threadIdx.x;
    const float cc = TWO_PI_F / (float)WIN;

    if (bx < 4096) {                       // ---- M1T[j][kk], irfft*synth
        int idx = bx * 256 + tid, j = idx >> 10, kk = idx & 1023;
        if ((j & 1) && j < 961) return;    // odd rows <961 never read
        float v = 0.f;
        if (j < WIN) {
            float w = 0.5f - 0.5f * __cosf(cc * (float)j);
            float dd = 0.f;
            int p = j & (HOP - 1);
            for (int r = 0; r < 4; ++r) {
                int ix = p + HOP * r;
                if (ix < WIN) {
                    float wi = 0.5f - 0.5f * __cosf(cc * (float)ix);
                    dd += wi * wi;
                }
            }
            float synth = w / dd;
            int k = kk >> 1, c = kk & 1;
            if (!(c == 1 && (k == 0 || k == 511))) {   // Im of DC/Nyquist ignored
                float a = (k == 0 || k == 511) ? (1.f / (float)WIN) : (2.f / (float)WIN);
                int m = (k * j) % WIN;                 // exact phase reduction
                float s, co;
                __sincosf((float)m * cc, &s, &co);
                v = a * synth * (c == 0 ? co : -s);
            }
        }
        M1T[idx] = (_Float16)v;
        return;
    }
    if (bx < 8192) {                       // ---- M2T[col][j], rfft*hann
        int idx = (bx - 4096) * 256 + tid, col = idx >> 10, j = idx & 1023;
        float v = 0.f;
        if (j < WIN) {
            float w = 0.5f - 0.5f * __cosf(cc * (float)j);
            int k = col >> 1, c = col & 1;
            int m = (k * j) % WIN;
            float s, co;
            __sincosf((float)m * cc, &s, &co);
            v = w * (c == 0 ? co : -s);
        }
        M2T[idx] = (_Float16)v;
        return;
    }
    // ---- pack_a: 1024 blocks (16 k-tiles x 64 batches)
    int bx2 = bx - 8192;
    int kt = bx2 >> 6, b = bx2 & 63;
    const float* base = in + ((size_t)b * 512 + kt * 32) * (T_IN * 2);
    for (int idx2 = tid; idx2 < 32 * 254; idx2 += 256)
        lds[idx2] = base[idx2];
    __syncthreads();
    for (int f = tid; f < T_IN * 64; f += 256) {
        int t = f >> 6, l = f & 63;
        int dk = l >> 1, c = l & 1;
        A1[(size_t)(b * T_IN + t) * NPAD + kt * 64 + l] =
            (_Float16)lds[dk * 254 + t * 2 + c];
    }
}

// ------------------------------- MFMA GEMM ---------------------------------
// 128x64 C-tile, BK=64, split-K over blockIdx.z (2 slices of 512).
// 4 waves (2 row-halves x 2 col-halves), per wave 4x2 tiles, 16 MFMA/K-iter.

__device__ __forceinline__ void stage16(const void* g, void* l) {
    __builtin_amdgcn_global_load_lds(
        (const __attribute__((address_space(1))) unsigned int*)g,
        (__attribute__((address_space(3))) unsigned int*)l, 16, 0, 0);
}

template <bool G2>
__global__ __launch_bounds__(256) void gemm_mfma(const _Float16* __restrict__ A,
                                                 const _Float16* __restrict__ B0,
                                                 void* __restrict__ Cv) {
    constexpr int BPITCH = G2 ? NPAD : 2 * NPAD;   // gemm1 B = even rows of M1T
    __shared__ __align__(16) _Float16 As[128 * 64];
    __shared__ __align__(16) _Float16 Bs[64 * 64];

    int tid  = threadIdx.x;
    int lane = tid & 63, wave = tid >> 6;
    int quad = lane >> 4, l16 = lane & 15;
    int rowOff = (wave >> 1) * 64, colOff = (wave & 1) * 32;
    int rowBase = blockIdx.y * 128, colBase = blockIdx.x * 64;
    int kbase = blockIdx.z * NE;

    // staging pointers: chunk f = u*256+tid -> row f>>3, k-off (f&7)*8,
    // LDS byte offset f*16 (wave-uniform base + lane*16: legal).
    const _Float16* Ag[4]; _Float16* Al[4];
    const _Float16* Bg[2]; _Float16* Bl[2];
#pragma unroll
    for (int u = 0; u < 4; ++u) {
        int f = u * 256 + tid, r = f >> 3, ko = (f & 7) * 8;
        Ag[u] = A + (size_t)(rowBase + r) * NPAD + kbase + ko;
        Al[u] = As + f * 8;
    }
#pragma unroll
    for (int u = 0; u < 2; ++u) {
        int f = u * 256 + tid, r = f >> 3, ko = (f & 7) * 8;
        Bg[u] = B0 + (size_t)(colBase + r) * BPITCH + kbase + ko;
        Bl[u] = Bs + f * 8;
    }

    f32x4 acc[4][2] = {};

    for (int k0 = 0; k0 < NE; k0 += 64) {
#pragma unroll
        for (int u = 0; u < 4; ++u) stage16(Ag[u] + k0, Al[u]);
#pragma unroll
        for (int u = 0; u < 2; ++u) stage16(Bg[u] + k0, Bl[u]);
        __syncthreads();

        half8 af[2][4], bf[2][2];
#pragma unroll
        for (int s = 0; s < 2; ++s) {
#pragma unroll
            for (int i = 0; i < 4; ++i)
                af[s][i] = *(const half8*)&As[(rowOff + i * 16 + l16) * 64 + s * 32 + quad * 8];
#pragma unroll
            for (int j = 0; j < 2; ++j)
                bf[s][j] = *(const half8*)&Bs[(colOff + j * 16 + l16) * 64 + s * 32 + quad * 8];
        }
#pragma unroll
        for (int s = 0; s < 2; ++s)
#pragma unroll
            for (int i = 0; i < 4; ++i)
#pragma unroll
                for (int j = 0; j < 2; ++j)
                    acc[i][j] = __builtin_amdgcn_mfma_f32_16x16x32_f16(af[s][i], bf[s][j], acc[i][j], 0, 0, 0);
        __syncthreads();
    }

    // C/D layout: col = l16, row = quad*4 + reg
#pragma unroll
    for (int i = 0; i < 4; ++i) {
#pragma unroll
        for (int j = 0; j < 2; ++j) {
            int col = colBase + colOff + j * 16 + l16;
#pragma unroll
            for (int rr = 0; rr < 4; ++rr) {
                int row = rowBase + rowOff + i * 16 + quad * 4 + rr;
                if (!G2) {
                    _Float16* fe = (_Float16*)Cv + (size_t)blockIdx.z * ROWS1P * NE;
                    fe[(size_t)row * NE + col] = (_Float16)acc[i][j][rr];
                } else if (row < ROWS2) {
                    int b = row / T_OUT, t2 = row % T_OUT;
                    int k = col >> 1, c = col & 1;
                    atomicAdd((float*)Cv + (((size_t)b * 512 + k) * T_OUT + t2) * 2 + c,
                              acc[i][j][rr]);
                }
            }
        }
    }
}

// ------------------------- fused OLA + decimate + frame --------------------
__global__ void ola_pack(const _Float16* __restrict__ fe0,
                         const _Float16* __restrict__ fe1,
                         const _Float16* __restrict__ A1,
                         const _Float16* __restrict__ M1T,
                         _Float16* __restrict__ fr) {
    int i = blockIdx.x * 256 + threadIdx.x;
    int b = blockIdx.y;
    if (i >= L_USE) return;

    float v = 0.f;
    if (i < HALF_KEPT) {                   // s = 2i even: compacted OLA
        int tmin = (i > 510) ? ((i - 383) >> 7) : 0;
        int tmax = i >> 7; if (tmax > T_IN - 1) tmax = T_IN - 1;
        for (int t = tmin; t <= tmax; ++t) {
            size_t idx = (size_t)(b * T_IN + t) * NE + (i - t * 128);
            v += (float)fe0[idx] + (float)fe1[idx];
        }
    } else {                               // tail: only t=126 contributes
        int s = i + HALF_KEPT;             // 33216..33245
        int p = s - 32256;                 // 960..989
        if (!(s & 1)) {
            size_t idx = (size_t)(b * T_IN + 126) * NE + (p >> 1);
            v = (float)fe0[idx] + (float)fe1[idx];
        } else {                           // odd p: direct 1024-dot
            const _Float16* ar = A1 + (size_t)(b * T_IN + 126) * NPAD;
            const _Float16* mr = M1T + (size_t)p * NPAD;
            float a0 = 0.f;
            for (int k = 0; k < NPAD; k += 8) {
                half8 av = *(const half8*)&ar[k];
                half8 mv = *(const half8*)&mr[k];
#pragma unroll
                for (int u = 0; u < 8; ++u)
                    a0 += (float)av[u] * (float)mv[u];
            }
            v = a0;
        }
    }

    _Float16 hv = (_Float16)v;
    int t2min = (i > WIN - 1) ? ((i - (WIN - 1) + HOP - 1) >> 8) : 0;
    int t2max = i >> 8; if (t2max > T_OUT - 1) t2max = T_OUT - 1;
    for (int t2 = t2min; t2 <= t2max; ++t2)
        fr[(size_t)(b * T_OUT + t2) * NPAD + (i - t2 * HOP)] = hv;
}

// ------------------------------- launcher ----------------------------------

extern "C" void kernel_launch(void* const* d_in, const int* in_sizes, int n_in,
                              void* d_out, int out_size, void* d_ws, size_t ws_size,
                              hipStream_t stream) {
    const float* in = (const float*)d_in[0];
    float* out = (float*)d_out;
    char* ws = (char*)d_ws;

    _Float16* M1T = (_Float16*)ws;                        // 2 MB
    _Float16* M2T = M1T + (size_t)NPAD * NPAD;            // 2 MB
    _Float16* A1  = M2T + (size_t)NPAD * NPAD;            // 16 MB
    _Float16* fr  = A1 + (size_t)ROWS1P * NPAD;           // 8 MB
    _Float16* fe  = fr + (size_t)ROWS2P * NPAD;           // 8+8 MB (z=0,1)

    hipMemsetAsync(out, 0, (size_t)out_size * sizeof(float), stream);
    prep<<<9216, 256, 0, stream>>>(in, M1T, M2T, A1);
    gemm_mfma<false><<<dim3(NE / 64, ROWS1P / 128, 2), 256, 0, stream>>>(A1, M1T, fe);
    ola_pack<<<dim3(65, NB), 256, 0, stream>>>(fe, fe + (size_t)ROWS1P * NE, A1, M1T, fr);
    gemm_mfma<true><<<dim3(NPAD / 64, ROWS2P / 128, 2), 256, 0, stream>>>(fr, M2T, out);
}

// Round 6
// 152.090 us; speedup vs baseline: 1.8531x; 1.8531x over previous
//
#include <hip/hip_runtime.h>

// ---------------------------------------------------------------------------
// Downsampling — fp16 MFMA. gemm2 operand-swapped for coalesced epilogue.
//   prep:    M1T (even rows + odd>=961), M2T, A1 transpose       [9216 blocks]
//   gemm1:   fe{0,1}[8192][512]f16 = A1 @ (even rows of M1T)^T, K split 2x512
//   ola_pack: fr[4096][1024]f16 = frame(decimate(OLA(fe0+fe1)))
//   gemm2:   D[kk][n] = M2T @ fr^T ; lane holds 4 consecutive kk rows ->
//            two float2 (Re,Im) writes; col=n contiguous across 16 lanes.
// ---------------------------------------------------------------------------

#define WIN       1022
#define HOP       256
#define T_IN      127
#define NB        64
#define NPAD      1024
#define NE        512       // even-compacted stage-1 columns; K per z-slice
#define T_OUT     62
#define HALF_KEPT 16608     // 33216/2
#define L_USE     16638     // kept samples beyond 16637 feed no output frame
#define ROWS1     8128
#define ROWS1P    8192
#define ROWS2     3968
#define ROWS2P    4096
#define TWO_PI_F  6.28318530717958647692f

typedef _Float16 half8 __attribute__((ext_vector_type(8)));
typedef float    f32x4 __attribute__((ext_vector_type(4)));

// ------------------------------- fused prep --------------------------------
__global__ __launch_bounds__(256) void prep(const float* __restrict__ in,
                                            _Float16* __restrict__ M1T,
                                            _Float16* __restrict__ M2T,
                                            _Float16* __restrict__ A1) {
    __shared__ float lds[32 * 254];
    int bx = blockIdx.x, tid = threadIdx.x;
    const float cc = TWO_PI_F / (float)WIN;

    if (bx < 4096) {                       // ---- M1T[j][kk], irfft*synth
        int idx = bx * 256 + tid, j = idx >> 10, kk = idx & 1023;
        if ((j & 1) && j < 961) return;    // odd rows <961 never read
        float v = 0.f;
        if (j < WIN) {
            float w = 0.5f - 0.5f * __cosf(cc * (float)j);
            float dd = 0.f;
            int p = j & (HOP - 1);
            for (int r = 0; r < 4; ++r) {
                int ix = p + HOP * r;
                if (ix < WIN) {
                    float wi = 0.5f - 0.5f * __cosf(cc * (float)ix);
                    dd += wi * wi;
                }
            }
            float synth = w / dd;
            int k = kk >> 1, c = kk & 1;
            if (!(c == 1 && (k == 0 || k == 511))) {   // Im of DC/Nyquist ignored
                float a = (k == 0 || k == 511) ? (1.f / (float)WIN) : (2.f / (float)WIN);
                int m = (k * j) % WIN;                 // exact phase reduction
                float s, co;
                __sincosf((float)m * cc, &s, &co);
                v = a * synth * (c == 0 ? co : -s);
            }
        }
        M1T[idx] = (_Float16)v;
        return;
    }
    if (bx < 8192) {                       // ---- M2T[col][j], rfft*hann
        int idx = (bx - 4096) * 256 + tid, col = idx >> 10, j = idx & 1023;
        float v = 0.f;
        if (j < WIN) {
            float w = 0.5f - 0.5f * __cosf(cc * (float)j);
            int k = col >> 1, c = col & 1;
            int m = (k * j) % WIN;
            float s, co;
            __sincosf((float)m * cc, &s, &co);
            v = w * (c == 0 ? co : -s);
        }
        M2T[idx] = (_Float16)v;
        return;
    }
    // ---- pack_a: 1024 blocks (16 k-tiles x 64 batches)
    int bx2 = bx - 8192;
    int kt = bx2 >> 6, b = bx2 & 63;
    const float* base = in + ((size_t)b * 512 + kt * 32) * (T_IN * 2);
    for (int idx2 = tid; idx2 < 32 * 254; idx2 += 256)
        lds[idx2] = base[idx2];
    __syncthreads();
    for (int f = tid; f < T_IN * 64; f += 256) {
        int t = f >> 6, l = f & 63;
        int dk = l >> 1, c = l & 1;
        A1[(size_t)(b * T_IN + t) * NPAD + kt * 64 + l] =
            (_Float16)lds[dk * 254 + t * 2 + c];
    }
}

// ------------------------------- MFMA GEMM ---------------------------------
// 128x64 C-tile, BK=64. gemm1: split-K over blockIdx.z (2 slices of 512).
// gemm2: A=M2T (M=1024 kk-rows), B=fr (N=4096 n-rows), full K=1024.

__device__ __forceinline__ void stage16(const void* g, void* l) {
    __builtin_amdgcn_global_load_lds(
        (const __attribute__((address_space(1))) unsigned int*)g,
        (__attribute__((address_space(3))) unsigned int*)l, 16, 0, 0);
}

template <bool G2>
__global__ __launch_bounds__(256) void gemm_mfma(const _Float16* __restrict__ A,
                                                 const _Float16* __restrict__ B0,
                                                 void* __restrict__ Cv) {
    constexpr int BPITCH = G2 ? NPAD : 2 * NPAD;   // gemm1 B = even rows of M1T
    constexpr int KTOT   = G2 ? NPAD : NE;
    __shared__ __align__(16) _Float16 As[128 * 64];
    __shared__ __align__(16) _Float16 Bs[64 * 64];

    int tid  = threadIdx.x;
    int lane = tid & 63, wave = tid >> 6;
    int quad = lane >> 4, l16 = lane & 15;
    int rowOff = (wave >> 1) * 64, colOff = (wave & 1) * 32;
    int rowBase = blockIdx.y * 128, colBase = blockIdx.x * 64;
    int kbase = G2 ? 0 : blockIdx.z * NE;

    const _Float16* Ag[4]; _Float16* Al[4];
    const _Float16* Bg[2]; _Float16* Bl[2];
#pragma unroll
    for (int u = 0; u < 4; ++u) {
        int f = u * 256 + tid, r = f >> 3, ko = (f & 7) * 8;
        Ag[u] = A + (size_t)(rowBase + r) * NPAD + kbase + ko;
        Al[u] = As + f * 8;
    }
#pragma unroll
    for (int u = 0; u < 2; ++u) {
        int f = u * 256 + tid, r = f >> 3, ko = (f & 7) * 8;
        Bg[u] = B0 + (size_t)(colBase + r) * BPITCH + kbase + ko;
        Bl[u] = Bs + f * 8;
    }

    f32x4 acc[4][2] = {};

    for (int k0 = 0; k0 < KTOT; k0 += 64) {
#pragma unroll
        for (int u = 0; u < 4; ++u) stage16(Ag[u] + k0, Al[u]);
#pragma unroll
        for (int u = 0; u < 2; ++u) stage16(Bg[u] + k0, Bl[u]);
        __syncthreads();

        half8 af[2][4], bf[2][2];
#pragma unroll
        for (int s = 0; s < 2; ++s) {
#pragma unroll
            for (int i = 0; i < 4; ++i)
                af[s][i] = *(const half8*)&As[(rowOff + i * 16 + l16) * 64 + s * 32 + quad * 8];
#pragma unroll
            for (int j = 0; j < 2; ++j)
                bf[s][j] = *(const half8*)&Bs[(colOff + j * 16 + l16) * 64 + s * 32 + quad * 8];
        }
#pragma unroll
        for (int s = 0; s < 2; ++s)
#pragma unroll
            for (int i = 0; i < 4; ++i)
#pragma unroll
                for (int j = 0; j < 2; ++j)
                    acc[i][j] = __builtin_amdgcn_mfma_f32_16x16x32_f16(af[s][i], bf[s][j], acc[i][j], 0, 0, 0);
        __syncthreads();
    }

    // C/D layout: col = l16, row = quad*4 + reg
#pragma unroll
    for (int i = 0; i < 4; ++i) {
#pragma unroll
        for (int j = 0; j < 2; ++j) {
            int col = colBase + colOff + j * 16 + l16;
            if (!G2) {
                _Float16* fe = (_Float16*)Cv + (size_t)blockIdx.z * ROWS1P * NE;
#pragma unroll
                for (int rr = 0; rr < 4; ++rr) {
                    int row = rowBase + rowOff + i * 16 + quad * 4 + rr;
                    fe[(size_t)row * NE + col] = (_Float16)acc[i][j][rr];
                }
            } else if (col < ROWS2) {
                // col = n = b*62+t2 ; rows = kk (consecutive): float2 Re/Im
                int b = col / T_OUT, t2 = col % T_OUT;
#pragma unroll
                for (int rr = 0; rr < 4; rr += 2) {
                    int row = rowBase + rowOff + i * 16 + quad * 4 + rr;  // even
                    int k = row >> 1;
                    float2 v = make_float2(acc[i][j][rr], acc[i][j][rr + 1]);
                    *(float2*)((float*)Cv + (((size_t)b * 512 + k) * T_OUT + t2) * 2) = v;
                }
            }
        }
    }
}

// ------------------------- fused OLA + decimate + frame --------------------
__global__ void ola_pack(const _Float16* __restrict__ fe0,
                         const _Float16* __restrict__ fe1,
                         const _Float16* __restrict__ A1,
                         const _Float16* __restrict__ M1T,
                         _Float16* __restrict__ fr) {
    int i = blockIdx.x * 256 + threadIdx.x;
    int b = blockIdx.y;
    if (i >= L_USE) return;

    float v = 0.f;
    if (i < HALF_KEPT) {                   // s = 2i even: compacted OLA
        int tmin = (i > 510) ? ((i - 383) >> 7) : 0;
        int tmax = i >> 7; if (tmax > T_IN - 1) tmax = T_IN - 1;
        for (int t = tmin; t <= tmax; ++t) {
            size_t idx = (size_t)(b * T_IN + t) * NE + (i - t * 128);
            v += (float)fe0[idx] + (float)fe1[idx];
        }
    } else {                               // tail: only t=126 contributes
        int s = i + HALF_KEPT;             // 33216..33245
        int p = s - 32256;                 // 960..989
        if (!(s & 1)) {
            size_t idx = (size_t)(b * T_IN + 126) * NE + (p >> 1);
            v = (float)fe0[idx] + (float)fe1[idx];
        } else {                           // odd p: direct 1024-dot
            const _Float16* ar = A1 + (size_t)(b * T_IN + 126) * NPAD;
            const _Float16* mr = M1T + (size_t)p * NPAD;
            float a0 = 0.f;
            for (int k = 0; k < NPAD; k += 8) {
                half8 av = *(const half8*)&ar[k];
                half8 mv = *(const half8*)&mr[k];
#pragma unroll
                for (int u = 0; u < 8; ++u)
                    a0 += (float)av[u] * (float)mv[u];
            }
            v = a0;
        }
    }

    _Float16 hv = (_Float16)v;
    int t2min = (i > WIN - 1) ? ((i - (WIN - 1) + HOP - 1) >> 8) : 0;
    int t2max = i >> 8; if (t2max > T_OUT - 1) t2max = T_OUT - 1;
    for (int t2 = t2min; t2 <= t2max; ++t2)
        fr[(size_t)(b * T_OUT + t2) * NPAD + (i - t2 * HOP)] = hv;
}

// ------------------------------- launcher ----------------------------------

extern "C" void kernel_launch(void* const* d_in, const int* in_sizes, int n_in,
                              void* d_out, int out_size, void* d_ws, size_t ws_size,
                              hipStream_t stream) {
    const float* in = (const float*)d_in[0];
    float* out = (float*)d_out;
    char* ws = (char*)d_ws;

    _Float16* M1T = (_Float16*)ws;                        // 2 MB
    _Float16* M2T = M1T + (size_t)NPAD * NPAD;            // 2 MB
    _Float16* A1  = M2T + (size_t)NPAD * NPAD;            // 16 MB
    _Float16* fr  = A1 + (size_t)ROWS1P * NPAD;           // 8 MB
    _Float16* fe  = fr + (size_t)ROWS2P * NPAD;           // 8+8 MB (z=0,1)

    prep<<<9216, 256, 0, stream>>>(in, M1T, M2T, A1);
    gemm_mfma<false><<<dim3(NE / 64, ROWS1P / 128, 2), 256, 0, stream>>>(A1, M1T, fe);
    ola_pack<<<dim3(65, NB), 256, 0, stream>>>(fe, fe + (size_t)ROWS1P * NE, A1, M1T, fr);
    // gemm2: A=M2T (kk rows), B=fr (n rows); grid x over n=4096, y over kk=1024
    gemm_mfma<true><<<dim3(ROWS2P / 64, NPAD / 128), 256, 0, stream>>>(M2T, fr, out);
}

// Round 7
// 146.508 us; speedup vs baseline: 1.9237x; 1.0381x over previous
//
#include <hip/hip_runtime.h>

// ---------------------------------------------------------------------------
// Downsampling — fp16 MFMA, XOR-swizzled LDS (bank-conflict-free frag reads).
//   prep:    M1T (even rows + odd>=961), M2T, A1 transpose       [9216 blocks]
//   gemm1:   fe{0,1}[8192][512]f16 = A1 @ (even rows of M1T)^T, K split 2x512
//   ola_pack: fr[4096][1024]f16 = frame(decimate(OLA(fe0+fe1)))
//   gemm2:   D[kk][n] = M2T @ fr^T ; coalesced float2 (Re,Im) epilogue.
// LDS swizzle: physical 8-half slot u holds logical slot u^(row&7).  Staging
// stays contiguous (only global source offset permutes — legal for
// global_load_lds); fragment reads spread across all 32 banks.
// ---------------------------------------------------------------------------

#define WIN       1022
#define HOP       256
#define T_IN      127
#define NB        64
#define NPAD      1024
#define NE        512       // even-compacted stage-1 columns; K per z-slice
#define T_OUT     62
#define HALF_KEPT 16608     // 33216/2
#define L_USE     16638     // kept samples beyond 16637 feed no output frame
#define ROWS1     8128
#define ROWS1P    8192
#define ROWS2     3968
#define ROWS2P    4096
#define TWO_PI_F  6.28318530717958647692f

typedef _Float16 half8 __attribute__((ext_vector_type(8)));
typedef float    f32x4 __attribute__((ext_vector_type(4)));

// ------------------------------- fused prep --------------------------------
__global__ __launch_bounds__(256) void prep(const float* __restrict__ in,
                                            _Float16* __restrict__ M1T,
                                            _Float16* __restrict__ M2T,
                                            _Float16* __restrict__ A1) {
    __shared__ float lds[32 * 254];
    int bx = blockIdx.x, tid = threadIdx.x;
    const float cc = TWO_PI_F / (float)WIN;

    if (bx < 4096) {                       // ---- M1T[j][kk], irfft*synth
        int idx = bx * 256 + tid, j = idx >> 10, kk = idx & 1023;
        if ((j & 1) && j < 961) return;    // odd rows <961 never read
        float v = 0.f;
        if (j < WIN) {
            float w = 0.5f - 0.5f * __cosf(cc * (float)j);
            float dd = 0.f;
            int p = j & (HOP - 1);
            for (int r = 0; r < 4; ++r) {
                int ix = p + HOP * r;
                if (ix < WIN) {
                    float wi = 0.5f - 0.5f * __cosf(cc * (float)ix);
                    dd += wi * wi;
                }
            }
            float synth = w / dd;
            int k = kk >> 1, c = kk & 1;
            if (!(c == 1 && (k == 0 || k == 511))) {   // Im of DC/Nyquist ignored
                float a = (k == 0 || k == 511) ? (1.f / (float)WIN) : (2.f / (float)WIN);
                int m = (k * j) % WIN;                 // exact phase reduction
                float s, co;
                __sincosf((float)m * cc, &s, &co);
                v = a * synth * (c == 0 ? co : -s);
            }
        }
        M1T[idx] = (_Float16)v;
        return;
    }
    if (bx < 8192) {                       // ---- M2T[col][j], rfft*hann
        int idx = (bx - 4096) * 256 + tid, col = idx >> 10, j = idx & 1023;
        float v = 0.f;
        if (j < WIN) {
            float w = 0.5f - 0.5f * __cosf(cc * (float)j);
            int k = col >> 1, c = col & 1;
            int m = (k * j) % WIN;
            float s, co;
            __sincosf((float)m * cc, &s, &co);
            v = w * (c == 0 ? co : -s);
        }
        M2T[idx] = (_Float16)v;
        return;
    }
    // ---- pack_a: 1024 blocks (16 k-tiles x 64 batches)
    int bx2 = bx - 8192;
    int kt = bx2 >> 6, b = bx2 & 63;
    const float* base = in + ((size_t)b * 512 + kt * 32) * (T_IN * 2);
    for (int idx2 = tid; idx2 < 32 * 254; idx2 += 256)
        lds[idx2] = base[idx2];
    __syncthreads();
    for (int f = tid; f < T_IN * 64; f += 256) {
        int t = f >> 6, l = f & 63;
        int dk = l >> 1, c = l & 1;
        A1[(size_t)(b * T_IN + t) * NPAD + kt * 64 + l] =
            (_Float16)lds[dk * 254 + t * 2 + c];
    }
}

// ------------------------------- MFMA GEMM ---------------------------------
// 128x64 C-tile, BK=64. gemm1: split-K over blockIdx.z (2 slices of 512).
// gemm2: A=M2T (M=1024 kk-rows), B=fr (N=4096 n-rows), full K=1024.
// LDS rows are 64 halves; 8-half chunk u of row r sits at physical u^(r&7).

__device__ __forceinline__ void stage16(const void* g, void* l) {
    __builtin_amdgcn_global_load_lds(
        (const __attribute__((address_space(1))) unsigned int*)g,
        (__attribute__((address_space(3))) unsigned int*)l, 16, 0, 0);
}

template <bool G2>
__global__ __launch_bounds__(256) void gemm_mfma(const _Float16* __restrict__ A,
                                                 const _Float16* __restrict__ B0,
                                                 void* __restrict__ Cv) {
    constexpr int BPITCH = G2 ? NPAD : 2 * NPAD;   // gemm1 B = even rows of M1T
    constexpr int KTOT   = G2 ? NPAD : NE;
    __shared__ __align__(16) _Float16 As[128 * 64];
    __shared__ __align__(16) _Float16 Bs[64 * 64];

    int tid  = threadIdx.x;
    int lane = tid & 63, wave = tid >> 6;
    int quad = lane >> 4, l16 = lane & 15;
    int rowOff = (wave >> 1) * 64, colOff = (wave & 1) * 32;
    int rowBase = blockIdx.y * 128, colBase = blockIdx.x * 64;
    int kbase = G2 ? 0 : blockIdx.z * NE;

    // staging: physical LDS chunk f (16 B) holds logical k-chunk (f&7)^(r&7)
    const _Float16* Ag[4]; _Float16* Al[4];
    const _Float16* Bg[2]; _Float16* Bl[2];
#pragma unroll
    for (int u = 0; u < 4; ++u) {
        int f = u * 256 + tid, r = f >> 3, ko = (((f & 7) ^ (r & 7))) * 8;
        Ag[u] = A + (size_t)(rowBase + r) * NPAD + kbase + ko;
        Al[u] = As + f * 8;
    }
#pragma unroll
    for (int u = 0; u < 2; ++u) {
        int f = u * 256 + tid, r = f >> 3, ko = (((f & 7) ^ (r & 7))) * 8;
        Bg[u] = B0 + (size_t)(colBase + r) * BPITCH + kbase + ko;
        Bl[u] = Bs + f * 8;
    }

    f32x4 acc[4][2] = {};

    for (int k0 = 0; k0 < KTOT; k0 += 64) {
#pragma unroll
        for (int u = 0; u < 4; ++u) stage16(Ag[u] + k0, Al[u]);
#pragma unroll
        for (int u = 0; u < 2; ++u) stage16(Bg[u] + k0, Bl[u]);
        __syncthreads();

        half8 af[2][4], bf[2][2];
#pragma unroll
        for (int s = 0; s < 2; ++s) {
#pragma unroll
            for (int i = 0; i < 4; ++i) {
                int row = rowOff + i * 16 + l16;
                af[s][i] = *(const half8*)&As[row * 64 + (((s * 4 + quad) ^ (row & 7)) * 8)];
            }
#pragma unroll
            for (int j = 0; j < 2; ++j) {
                int row = colOff + j * 16 + l16;
                bf[s][j] = *(const half8*)&Bs[row * 64 + (((s * 4 + quad) ^ (row & 7)) * 8)];
            }
        }
#pragma unroll
        for (int s = 0; s < 2; ++s)
#pragma unroll
            for (int i = 0; i < 4; ++i)
#pragma unroll
                for (int j = 0; j < 2; ++j)
                    acc[i][j] = __builtin_amdgcn_mfma_f32_16x16x32_f16(af[s][i], bf[s][j], acc[i][j], 0, 0, 0);
        __syncthreads();
    }

    // C/D layout: col = l16, row = quad*4 + reg
#pragma unroll
    for (int i = 0; i < 4; ++i) {
#pragma unroll
        for (int j = 0; j < 2; ++j) {
            int col = colBase + colOff + j * 16 + l16;
            if (!G2) {
                _Float16* fe = (_Float16*)Cv + (size_t)blockIdx.z * ROWS1P * NE;
#pragma unroll
                for (int rr = 0; rr < 4; ++rr) {
                    int row = rowBase + rowOff + i * 16 + quad * 4 + rr;
                    fe[(size_t)row * NE + col] = (_Float16)acc[i][j][rr];
                }
            } else if (col < ROWS2) {
                // col = n = b*62+t2 ; rows = kk (consecutive): float2 Re/Im
                int b = col / T_OUT, t2 = col % T_OUT;
#pragma unroll
                for (int rr = 0; rr < 4; rr += 2) {
                    int row = rowBase + rowOff + i * 16 + quad * 4 + rr;  // even
                    int k = row >> 1;
                    float2 v = make_float2(acc[i][j][rr], acc[i][j][rr + 1]);
                    *(float2*)((float*)Cv + (((size_t)b * 512 + k) * T_OUT + t2) * 2) = v;
                }
            }
        }
    }
}

// ------------------------- fused OLA + decimate + frame --------------------
__global__ void ola_pack(const _Float16* __restrict__ fe0,
                         const _Float16* __restrict__ fe1,
                         const _Float16* __restrict__ A1,
                         const _Float16* __restrict__ M1T,
                         _Float16* __restrict__ fr) {
    int i = blockIdx.x * 256 + threadIdx.x;
    int b = blockIdx.y;
    if (i >= L_USE) return;

    float v = 0.f;
    if (i < HALF_KEPT) {                   // s = 2i even: compacted OLA
        int tmin = (i > 510) ? ((i - 383) >> 7) : 0;
        int tmax = i >> 7; if (tmax > T_IN - 1) tmax = T_IN - 1;
        for (int t = tmin; t <= tmax; ++t) {
            size_t idx = (size_t)(b * T_IN + t) * NE + (i - t * 128);
            v += (float)fe0[idx] + (float)fe1[idx];
        }
    } else {                               // tail: only t=126 contributes
        int s = i + HALF_KEPT;             // 33216..33245
        int p = s - 32256;                 // 960..989
        if (!(s & 1)) {
            size_t idx = (size_t)(b * T_IN + 126) * NE + (p >> 1);
            v = (float)fe0[idx] + (float)fe1[idx];
        } else {                           // odd p: direct 1024-dot
            const _Float16* ar = A1 + (size_t)(b * T_IN + 126) * NPAD;
            const _Float16* mr = M1T + (size_t)p * NPAD;
            float a0 = 0.f;
            for (int k = 0; k < NPAD; k += 8) {
                half8 av = *(const half8*)&ar[k];
                half8 mv = *(const half8*)&mr[k];
#pragma unroll
                for (int u = 0; u < 8; ++u)
                    a0 += (float)av[u] * (float)mv[u];
            }
            v = a0;
        }
    }

    _Float16 hv = (_Float16)v;
    int t2min = (i > WIN - 1) ? ((i - (WIN - 1) + HOP - 1) >> 8) : 0;
    int t2max = i >> 8; if (t2max > T_OUT - 1) t2max = T_OUT - 1;
    for (int t2 = t2min; t2 <= t2max; ++t2)
        fr[(size_t)(b * T_OUT + t2) * NPAD + (i - t2 * HOP)] = hv;
}

// ------------------------------- launcher ----------------------------------

extern "C" void kernel_launch(void* const* d_in, const int* in_sizes, int n_in,
                              void* d_out, int out_size, void* d_ws, size_t ws_size,
                              hipStream_t stream) {
    const float* in = (const float*)d_in[0];
    float* out = (float*)d_out;
    char* ws = (char*)d_ws;

    _Float16* M1T = (_Float16*)ws;                        // 2 MB
    _Float16* M2T = M1T + (size_t)NPAD * NPAD;            // 2 MB
    _Float16* A1  = M2T + (size_t)NPAD * NPAD;            // 16 MB
    _Float16* fr  = A1 + (size_t)ROWS1P * NPAD;           // 8 MB
    _Float16* fe  = fr + (size_t)ROWS2P * NPAD;           // 8+8 MB (z=0,1)

    prep<<<9216, 256, 0, stream>>>(in, M1T, M2T, A1);
    gemm_mfma<false><<<dim3(NE / 64, ROWS1P / 128, 2), 256, 0, stream>>>(A1, M1T, fe);
    ola_pack<<<dim3(65, NB), 256, 0, stream>>>(fe, fe + (size_t)ROWS1P * NE, A1, M1T, fr);
    // gemm2: A=M2T (kk rows), B=fr (n rows); grid x over n=4096, y over kk=1024
    gemm_mfma<true><<<dim3(ROWS2P / 64, NPAD / 128), 256, 0, stream>>>(M2T, fr, out);
}